// Round 8
// baseline (74.717 us; speedup 1.0000x reference)
//
#include <hip/hip_runtime.h>

// Problem constants (match reference setup_inputs)
constexpr int B  = 16;
constexpr int T  = 32;
constexpr int NB = 8;
constexpr int L  = 128;
constexpr int V  = 50000;
constexpr int P  = NB * L;            // 1024 contributions per (b,t) row

constexpr int NCHUNK = 4;             // vocab chunks per row
constexpr int CHUNK  = V / NCHUNK;    // 12500 floats = 50 KB per chunk
constexpr int CHUNK4 = CHUNK / 4;     // 3125 float4 (offset 50000B %16==0)
constexpr int NBLK   = B * T * NCHUNK; // 2048 = exactly 8 blocks/CU

typedef float f32x4 __attribute__((ext_vector_type(4)));

// No LDS. Each block owns one 50 KB output chunk:
//   1) stream ZEROS straight to global — dependency-free dwordx4 stores,
//      structurally identical to the vendor fill kernel (the measured
//      6.5-6.9 TB/s ceiling). This is the dominant 102.4 MB of traffic.
//   2) __syncthreads() — drains only this block's ~12 stores/thread to L2
//      (write acceptance), hidden by the other 7 resident blocks/CU.
//   3) global atomicAdd of the ~256 in-range contributions onto the
//      just-zeroed, still-L2-hot lines. Atomics execute at L2; working set
//      per CU is 8x50 KB = 400 KB, far inside the 4 MB/XCD L2.
// Differs from the failed round-1 global-atomic variant by 20x smaller
// per-block drain and an L2-resident atomic target set. No LDS round-trip:
// stores never wait on ds_read, and occupancy is register-bound only.
__global__ __launch_bounds__(256) void fused_direct_scatter_kernel(
    const float* __restrict__ bw,   // (B,T,NB)
    const float* __restrict__ att,  // (B,T,NB,L) == (B,T,P)
    const int*   __restrict__ idx,  // (B,NB,L)   == (B,P)
    float*       __restrict__ out)  // (B,T,V)
{
    const int blk   = blockIdx.x;        // bt*NCHUNK + chunk
    const int bt    = blk >> 2;          // / NCHUNK
    const int chunk = blk & (NCHUNK - 1);
    const int b     = bt >> 5;           // / T (T==32)
    const int tid   = threadIdx.x;       // 0..255
    const int lo    = chunk * CHUNK;

    // Issue input loads first so they're in flight under the zero stream.
    const float* attRow = att + bt * P;
    const float* bwRow  = bw  + bt * NB;
    const int*   idxRow = idx + b  * P;
    float val[4];
    int   v[4];
#pragma unroll
    for (int k = 0; k < 4; ++k) {
        const int p = tid + k * 256;
        val[k] = attRow[p] * bwRow[p >> 7];   // p>>7 == p/L == nb
        v[k]   = idxRow[p] - lo;              // position within this chunk
    }

    // Stream zeros to this block's global chunk: pure dependency-free
    // dwordx4 stores (the fill-kernel pattern).
    float* rowc = out + (size_t)bt * V + lo;
    f32x4* dst4 = reinterpret_cast<f32x4*>(rowc);
    const f32x4 z = {0.f, 0.f, 0.f, 0.f};
    for (int i = tid; i < CHUNK4; i += 256)
        dst4[i] = z;

    __syncthreads();  // vmcnt(0) drain: zeros accepted at L2 (coherence pt)

    // Scatter the in-range subset (~1/4) onto L2-hot lines.
#pragma unroll
    for (int k = 0; k < 4; ++k)
        if ((unsigned)v[k] < (unsigned)CHUNK)
            atomicAdd(&rowc[v[k]], val[k]);
}

extern "C" void kernel_launch(void* const* d_in, const int* in_sizes, int n_in,
                              void* d_out, int out_size, void* d_ws, size_t ws_size,
                              hipStream_t stream) {
    const float* bw  = (const float*)d_in[0];
    const float* att = (const float*)d_in[1];
    const int*   idx = (const int*)d_in[2];
    float* out = (float*)d_out;

    fused_direct_scatter_kernel<<<NBLK, 256, 0, stream>>>(bw, att, idx, out);
}

// Round 9
// 26.854 us; speedup vs baseline: 2.7823x; 2.7823x over previous
//
#include <hip/hip_runtime.h>

// Problem constants (match reference setup_inputs)
constexpr int B  = 16;
constexpr int T  = 32;
constexpr int NB = 8;
constexpr int L  = 128;
constexpr int V  = 50000;
constexpr int P  = NB * L;            // 1024 contributions per (b,t) row

constexpr int NCHUNK = 4;             // vocab chunks per row
constexpr int CHUNK  = V / NCHUNK;    // 12500 floats = 50 KB
constexpr int CHUNK4 = CHUNK / 4;     // 3125 float4 (offset 50000B %16==0)
constexpr int NBLK   = B * T * NCHUNK; // 2048 blocks

typedef float f32x4 __attribute__((ext_vector_type(4)));

// A/B experiment vs round 7: identical bulk-store structure, but the sparse
// touch uses LDS accumulate + plain overwrite stores instead of global
// atomicAdd.
//   1) Stream ZEROS straight to global — dependency-free dwordx4 stores,
//      the exact vendor-fill pattern (6.6 TB/s measured). Issued FIRST so
//      nothing delays the bulk stream. LDS zeroing + input loads overlap
//      (separate pipes).
//   2) barrier (drains zero stream to L2 = coherence point).
//   3) LDS scatter via ds atomics (resolves ~10 duplicate idx per row).
//   4) barrier (lgkm only; vmcnt already drained).
//   5) Scan LDS; for the ~2% nonzero slots, plain dword overwrite-store
//      onto the just-zeroed L2-dirty lines. Ordering vs the zeros is
//      guaranteed by the vmcnt(0) drain at step 2. Untouched slots are
//      exactly 0.0f (never written), so !=0 is an exact filter; a genuine
//      0.0 contribution skipped here leaves the correct 0.0 from phase 1.
__global__ __launch_bounds__(256) void fused_zstream_scatter_kernel(
    const float* __restrict__ bw,   // (B,T,NB)
    const float* __restrict__ att,  // (B,T,NB,L) == (B,T,P)
    const int*   __restrict__ idx,  // (B,NB,L)   == (B,P)
    float*       __restrict__ out)  // (B,T,V)
{
    __shared__ float buf[CHUNK];

    const int blk   = blockIdx.x;        // bt*NCHUNK + chunk
    const int bt    = blk >> 2;          // / NCHUNK
    const int chunk = blk & (NCHUNK - 1);
    const int b     = bt >> 5;           // / T (T==32)
    const int tid   = threadIdx.x;       // 0..255
    const int lo    = chunk * CHUNK;

    float* rowc = out + (size_t)bt * V + lo;
    f32x4* dst4 = reinterpret_cast<f32x4*>(rowc);
    f32x4* buf4 = reinterpret_cast<f32x4*>(buf);
    const f32x4 z = {0.f, 0.f, 0.f, 0.f};

    // Phase 1a: bulk zero stream to global (dependency-free, fill-like).
    for (int i = tid; i < CHUNK4; i += 256)
        dst4[i] = z;

    // Phase 1b: zero LDS (DS pipe, overlaps the global stores).
    for (int i = tid; i < CHUNK4; i += 256)
        buf4[i] = z;

    // Phase 1c: load this row's 1024 contributions.
    const float* attRow = att + bt * P;
    const float* bwRow  = bw  + bt * NB;
    const int*   idxRow = idx + b  * P;
    float val[4];
    int   v[4];
#pragma unroll
    for (int k = 0; k < 4; ++k) {
        const int p = tid + k * 256;
        val[k] = attRow[p] * bwRow[p >> 7];   // p>>7 == p/L == nb
        v[k]   = idxRow[p] - lo;              // position within this chunk
    }

    __syncthreads();  // zeros (global+LDS) complete; loads in regs

    // Phase 2: scatter the in-range subset (~1/4) into LDS.
#pragma unroll
    for (int k = 0; k < 4; ++k)
        if ((unsigned)v[k] < (unsigned)CHUNK)
            atomicAdd(&buf[v[k]], val[k]);

    __syncthreads();  // scatter visible (lgkm-only drain)

    // Phase 3: sparse overwrite of nonzero slots (plain stores, no atomics).
    for (int i = tid; i < CHUNK4; i += 256) {
        f32x4 x = buf4[i];
        if (x.x != 0.f) rowc[4 * i + 0] = x.x;
        if (x.y != 0.f) rowc[4 * i + 1] = x.y;
        if (x.z != 0.f) rowc[4 * i + 2] = x.z;
        if (x.w != 0.f) rowc[4 * i + 3] = x.w;
    }
}

extern "C" void kernel_launch(void* const* d_in, const int* in_sizes, int n_in,
                              void* d_out, int out_size, void* d_ws, size_t ws_size,
                              hipStream_t stream) {
    const float* bw  = (const float*)d_in[0];
    const float* att = (const float*)d_in[1];
    const int*   idx = (const int*)d_in[2];
    float* out = (float*)d_out;

    fused_zstream_scatter_kernel<<<NBLK, 256, 0, stream>>>(bw, att, idx, out);
}

// Round 10
// 21.015 us; speedup vs baseline: 3.5554x; 1.2778x over previous
//
#include <hip/hip_runtime.h>

// Problem constants (match reference setup_inputs)
constexpr int B  = 16;
constexpr int T  = 32;
constexpr int NB = 8;
constexpr int L  = 128;
constexpr int V  = 50000;
constexpr int P  = NB * L;            // 1024 contributions per (b,t) row

constexpr int NCHUNK = 10;            // vocab chunks per row
constexpr int CHUNK  = V / NCHUNK;    // 5000 floats = 20000 B LDS
constexpr int CHUNK4 = CHUNK / 4;     // 1250 float4 per chunk
constexpr int NASG   = B * T * NCHUNK;     // 5120 chunk-assignments
constexpr int ASG_PER_BLK = 4;             // each block does 4 consecutive
constexpr int NBLK   = NASG / ASG_PER_BLK; // 1280 = 5 blocks/CU resident

typedef float f32x4 __attribute__((ext_vector_type(4)));

// LDS-only barrier: waits DS ops (lgkmcnt) but does NOT drain global
// stores (vmcnt) — __syncthreads() would emit s_waitcnt vmcnt(0) and
// convoy all 8 lockstep blocks/CU on HBM write completion every phase.
// Global stores need no intra-kernel ordering here: no block ever reads
// another block's output region, and end-of-kernel drain is automatic.
__device__ __forceinline__ void lds_barrier() {
    asm volatile("s_waitcnt lgkmcnt(0)" ::: "memory");
    __builtin_amdgcn_s_barrier();
    asm volatile("" ::: "memory");
}

// Round-6 structure (best: 20.96 us) + lgkm-only barriers: iteration j's
// 20 KB of global stores drain lazily under iteration j+1's zero/load/
// scatter phases — no vmcnt(0) anywhere in the loop (the "counted vmcnt,
// never drain" principle). Per assignment: zero LDS || load row inputs ->
// lds_barrier -> ds-atomic scatter (~1/10 in range, ~10 dup/row) ->
// lds_barrier -> ds_read_b128 + global_store_dwordx4 stream ->
// lds_barrier (WAR: all waves' ds_reads done before re-zero).
__global__ __launch_bounds__(256) void fused_lds_scatter_kernel(
    const float* __restrict__ bw,   // (B,T,NB)
    const float* __restrict__ att,  // (B,T,NB,L) == (B,T,P)
    const int*   __restrict__ idx,  // (B,NB,L)   == (B,P)
    float*       __restrict__ out)  // (B,T,V)
{
    __shared__ float buf[CHUNK];
    f32x4* buf4 = reinterpret_cast<f32x4*>(buf);
    const int tid = threadIdx.x;    // 0..255

    for (int j = 0; j < ASG_PER_BLK; ++j) {
        const int asg   = blockIdx.x * ASG_PER_BLK + j;  // contiguous output
        const int bt    = asg / NCHUNK;
        const int chunk = asg - bt * NCHUNK;
        const int b     = bt >> 5;           // / T (T==32)
        const int lo    = chunk * CHUNK;

        // Zero LDS chunk (ds_write_b128); prev iter's stores still in flight.
        const f32x4 z = {0.f, 0.f, 0.f, 0.f};
        for (int i = tid; i < CHUNK4; i += 256)
            buf4[i] = z;

        // Load this row's 1024 contributions (coalesced; L2/L3-hot after
        // first pass). Compiler inserts counted vmcnt before first use.
        const float* attRow = att + bt * P;
        const float* bwRow  = bw  + bt * NB;
        const int*   idxRow = idx + b  * P;
        float val[4];
        int   v[4];
#pragma unroll
        for (int k = 0; k < 4; ++k) {
            const int p = tid + k * 256;
            val[k] = attRow[p] * bwRow[p >> 7];   // p>>7 == p/L == nb
            v[k]   = idxRow[p] - lo;              // position within chunk
        }

        lds_barrier();  // zeros visible (lgkm only — stores keep draining)

        // Scatter the in-range subset into LDS (ds atomics).
#pragma unroll
        for (int k = 0; k < 4; ++k)
            if ((unsigned)v[k] < (unsigned)CHUNK)
                atomicAdd(&buf[v[k]], val[k]);

        lds_barrier();  // scatter visible

        // Stream chunk to global: ds_read_b128 -> global_store_dwordx4.
        // Stores are fire-and-forget; nothing in the loop waits on them.
        f32x4* dst = reinterpret_cast<f32x4*>(out + (size_t)bt * V + lo);
        for (int i = tid; i < CHUNK4; i += 256)
            dst[i] = buf4[i];

        if (j + 1 < ASG_PER_BLK)
            lds_barrier();  // WAR: ds_reads complete before re-zeroing buf
    }
}

extern "C" void kernel_launch(void* const* d_in, const int* in_sizes, int n_in,
                              void* d_out, int out_size, void* d_ws, size_t ws_size,
                              hipStream_t stream) {
    const float* bw  = (const float*)d_in[0];
    const float* att = (const float*)d_in[1];
    const int*   idx = (const int*)d_in[2];
    float* out = (float*)d_out;

    fused_lds_scatter_kernel<<<NBLK, 256, 0, stream>>>(bw, att, idx, out);
}